// Round 6
// baseline (259.335 us; speedup 1.0000x reference)
//
#include <hip/hip_runtime.h>

#define N_ITEMS 100000
#define HID 128
#define NNZ_T 1600000
#define GEMM_BLOCKS 1563           // ceil(100000/64)
#define RP_BLOCKS 391              // ceil(100001/256)

typedef unsigned short ushort_t;
typedef unsigned int uint_t;
typedef short bf16x8 __attribute__((ext_vector_type(8)));
typedef float f32x4 __attribute__((ext_vector_type(4)));

static __device__ __forceinline__ ushort_t f32_to_bf16(float f) {
    uint_t u = __float_as_uint(f);
    uint_t r = (u + 0x7FFFu + ((u >> 16) & 1u)) >> 16;   // RNE
    return (ushort_t)r;
}

// === fused: [blocks 0..GEMM_BLOCKS) support GEMM | [GEMM_BLOCKS..) row_ptr ===
// GEMM: S = X @ W^T + b via mfma_f32_16x16x32_bf16 with SWAPPED operands:
//   mfma(A=W_frag, B=X_frag) -> D[i=W-row(out col)][j=item]
//   lane(q=lane>>4, m=lane&15) holds items row0+m, cols nt*16+q*4..+3 (4 regs)
//   -> epilogue packs 4 bf16 -> one 8B store per nt (vs 32 scalar 2B stores).
// W converted fp32->bf16 in-register (no prep kernel, W lives in L1/L2).
__global__ __launch_bounds__(256) void gemm_rowptr(
    const float* __restrict__ X, const float* __restrict__ W,
    const float* __restrict__ bias, const int* __restrict__ rows,
    ushort_t* __restrict__ S, int* __restrict__ row_ptr) {

    if (blockIdx.x >= GEMM_BLOCKS) {
        // --- row_ptr[r] = lower_bound(rows, r), rows sorted ascending ---
        int r = (blockIdx.x - GEMM_BLOCKS) * 256 + threadIdx.x;
        if (r > N_ITEMS) return;
        int lo = 0, hi = NNZ_T;
        while (lo < hi) {
            int mid = (lo + hi) >> 1;
            if (rows[mid] < r) lo = mid + 1; else hi = mid;
        }
        row_ptr[r] = lo;
        return;
    }

    const int lane = threadIdx.x & 63;
    const int wave = threadIdx.x >> 6;
    const int m = lane & 15;          // item-within-tile AND W-row-within-tile
    const int q = lane >> 4;
    const int row0 = blockIdx.x * 64 + wave * 16;

    int arow = row0 + m;
    if (arow >= N_ITEMS) arow = N_ITEMS - 1;          // clamp (stores guarded)

    f32x4 acc[8] = {};

#pragma unroll
    for (int kb = 0; kb < 4; ++kb) {
        const int k0 = kb * 32 + q * 8;
        // X fragment (B-operand): item row0+m, k = k0..k0+7
        float4 a0 = *(const float4*)&X[(size_t)arow * HID + k0];
        float4 a1 = *(const float4*)&X[(size_t)arow * HID + k0 + 4];
        bf16x8 xf;
        xf[0] = (short)f32_to_bf16(a0.x); xf[1] = (short)f32_to_bf16(a0.y);
        xf[2] = (short)f32_to_bf16(a0.z); xf[3] = (short)f32_to_bf16(a0.w);
        xf[4] = (short)f32_to_bf16(a1.x); xf[5] = (short)f32_to_bf16(a1.y);
        xf[6] = (short)f32_to_bf16(a1.z); xf[7] = (short)f32_to_bf16(a1.w);
#pragma unroll
        for (int nt = 0; nt < 8; ++nt) {
            // W fragment (A-operand): W-row nt*16+m, k = k0..k0+7 (fp32 -> bf16)
            float4 w0 = *(const float4*)&W[(size_t)(nt * 16 + m) * HID + k0];
            float4 w1 = *(const float4*)&W[(size_t)(nt * 16 + m) * HID + k0 + 4];
            bf16x8 wf;
            wf[0] = (short)f32_to_bf16(w0.x); wf[1] = (short)f32_to_bf16(w0.y);
            wf[2] = (short)f32_to_bf16(w0.z); wf[3] = (short)f32_to_bf16(w0.w);
            wf[4] = (short)f32_to_bf16(w1.x); wf[5] = (short)f32_to_bf16(w1.y);
            wf[6] = (short)f32_to_bf16(w1.z); wf[7] = (short)f32_to_bf16(w1.w);
            acc[nt] = __builtin_amdgcn_mfma_f32_16x16x32_bf16(wf, xf, acc[nt], 0, 0, 0);
        }
    }

    const int srow = row0 + m;
    const bool ok = srow < N_ITEMS;
#pragma unroll
    for (int nt = 0; nt < 8; ++nt) {
        const int c0 = nt * 16 + q * 4;               // 4 consecutive out cols
        float4 bv = *(const float4*)&bias[c0];
        ushort_t h0 = f32_to_bf16(acc[nt][0] + bv.x);
        ushort_t h1 = f32_to_bf16(acc[nt][1] + bv.y);
        ushort_t h2 = f32_to_bf16(acc[nt][2] + bv.z);
        ushort_t h3 = f32_to_bf16(acc[nt][3] + bv.w);
        uint2 pk;
        pk.x = (uint_t)h0 | ((uint_t)h1 << 16);
        pk.y = (uint_t)h2 | ((uint_t)h3 << 16);
        if (ok) *(uint2*)&S[(size_t)srow * HID + c0] = pk;
    }
}

// === out[row] = sum vals*S[cols] over CSR segment ===
// One wave per ROW PAIR; lane owns 2 columns. Padded clamped batches of 8 per
// row -> 16 independent 256B wave-gathers always in flight (remainder included;
// padding clamps to the row's last edge = same cache line, weight 0).
// Branch-free consume, no atomics, two float2 stores (empty rows store 0).
__global__ __launch_bounds__(256) void spmm_csr(
    const int* __restrict__ cols, const float* __restrict__ vals,
    const int* __restrict__ row_ptr, const ushort_t* __restrict__ S,
    float* __restrict__ out) {
    const int lane = threadIdx.x & 63;
    const int wid = blockIdx.x * 4 + ((threadIdx.x >> 6) & 3);
    const int r0 = wid * 2;
    if (r0 >= N_ITEMS) return;

    const int p0 = row_ptr[r0];
    const int p1 = row_ptr[r0 + 1];
    const int p2 = row_ptr[r0 + 2];                   // r0+1 < N always (N even)
    const int la = (p1 > p0) ? p1 - 1 : 0;            // clamp targets
    const int lb = (p2 > p1) ? p2 - 1 : 0;
    const int nb = max(p1 - p0, p2 - p1);

    const uint_t off = 2 * lane;
    float2 acc0 = make_float2(0.f, 0.f);
    float2 acc1 = make_float2(0.f, 0.f);

    for (int b = 0; b < nb; b += 8) {
        uint_t u0[8], u1[8];
        float v0[8], v1[8];
#pragma unroll
        for (int j = 0; j < 8; ++j) {                 // 16 gathers in flight
            int ia = p0 + b + j;
            int ib = p1 + b + j;
            bool oka = ia < p1, okb = ib < p2;
            ia = min(ia, la);
            ib = min(ib, lb);
            int ca = cols[ia], cb = cols[ib];
            v0[j] = oka ? vals[ia] : 0.f;
            v1[j] = okb ? vals[ib] : 0.f;
            u0[j] = *(const uint_t*)&S[(size_t)ca * HID + off];
            u1[j] = *(const uint_t*)&S[(size_t)cb * HID + off];
        }
#pragma unroll
        for (int j = 0; j < 8; ++j) {
            acc0.x = fmaf(v0[j], __uint_as_float(u0[j] << 16), acc0.x);
            acc0.y = fmaf(v0[j], __uint_as_float(u0[j] & 0xFFFF0000u), acc0.y);
            acc1.x = fmaf(v1[j], __uint_as_float(u1[j] << 16), acc1.x);
            acc1.y = fmaf(v1[j], __uint_as_float(u1[j] & 0xFFFF0000u), acc1.y);
        }
    }
    *(float2*)&out[(size_t)r0 * HID + off] = acc0;
    *(float2*)&out[(size_t)(r0 + 1) * HID + off] = acc1;
}

extern "C" void kernel_launch(void* const* d_in, const int* in_sizes, int n_in,
                              void* d_out, int out_size, void* d_ws, size_t ws_size,
                              hipStream_t stream) {
    const float* X    = (const float*)d_in[0];
    const int*   rows = (const int*)  d_in[1];
    const int*   cols = (const int*)  d_in[2];
    const float* vals = (const float*)d_in[3];
    const float* W    = (const float*)d_in[4];
    const float* bias = (const float*)d_in[5];
    float* out = (float*)d_out;

    ushort_t* S       = (ushort_t*)d_ws;                    // 25.6 MB bf16
    int*      row_ptr = (int*)(S + (size_t)N_ITEMS * HID);  // 400 KB

    gemm_rowptr<<<GEMM_BLOCKS + RP_BLOCKS, 256, 0, stream>>>(X, W, bias, rows, S, row_ptr);
    spmm_csr<<<(N_ITEMS / 2 + 3) / 4, 256, 0, stream>>>(cols, vals, row_ptr, S, out);
}

// Round 7
// 215.624 us; speedup vs baseline: 1.2027x; 1.2027x over previous
//
#include <hip/hip_runtime.h>

#define N_ITEMS 100000
#define HID 128
#define NNZ_T 1600000
#define PREPW_BLOCKS 64            // 16384 / 256
#define RP_BLOCKS 391              // ceil(100001/256)

typedef unsigned short ushort_t;
typedef unsigned int uint_t;
typedef short bf16x8 __attribute__((ext_vector_type(8)));
typedef float f32x4 __attribute__((ext_vector_type(4)));

static __device__ __forceinline__ ushort_t f32_to_bf16(float f) {
    uint_t u = __float_as_uint(f);
    uint_t r = (u + 0x7FFFu + ((u >> 16) & 1u)) >> 16;   // RNE
    return (ushort_t)r;
}

// === prep: [0..PREPW_BLOCKS) W fp32->bf16 | [PREPW_BLOCKS..) row_ptr ===
__global__ void prep(const float* __restrict__ W, const int* __restrict__ rows,
                     ushort_t* __restrict__ Wb, int* __restrict__ row_ptr) {
    if (blockIdx.x < PREPW_BLOCKS) {
        int i = blockIdx.x * 256 + threadIdx.x;
        Wb[i] = f32_to_bf16(W[i]);
        return;
    }
    int r = (blockIdx.x - PREPW_BLOCKS) * 256 + threadIdx.x;
    if (r > N_ITEMS) return;
    int lo = 0, hi = NNZ_T;
    while (lo < hi) {                       // lower_bound(rows, r), rows sorted
        int mid = (lo + hi) >> 1;
        if (rows[mid] < r) lo = mid + 1; else hi = mid;
    }
    row_ptr[r] = lo;
}

// === S = X @ W^T + b via mfma_f32_16x16x32_bf16, swapped operands ===
// mfma(A=W_frag, B=X_frag): lane(q=lane>>4,m=lane&15) -> item row0+m,
// out-cols nt*16+q*4..+3 => epilogue = 8 packed 8B stores per lane.
__global__ __launch_bounds__(256) void gemm_mfma(
    const float* __restrict__ X, const ushort_t* __restrict__ Wb,
    const float* __restrict__ bias, ushort_t* __restrict__ S) {
    const int lane = threadIdx.x & 63;
    const int wave = threadIdx.x >> 6;
    const int m = lane & 15;
    const int q = lane >> 4;
    const int row0 = blockIdx.x * 64 + wave * 16;

    int arow = row0 + m;
    if (arow >= N_ITEMS) arow = N_ITEMS - 1;          // clamp (stores guarded)

    f32x4 acc[8] = {};

#pragma unroll
    for (int kb = 0; kb < 4; ++kb) {
        const int k0 = kb * 32 + q * 8;
        float4 a0 = *(const float4*)&X[(size_t)arow * HID + k0];
        float4 a1 = *(const float4*)&X[(size_t)arow * HID + k0 + 4];
        bf16x8 xf;
        xf[0] = (short)f32_to_bf16(a0.x); xf[1] = (short)f32_to_bf16(a0.y);
        xf[2] = (short)f32_to_bf16(a0.z); xf[3] = (short)f32_to_bf16(a0.w);
        xf[4] = (short)f32_to_bf16(a1.x); xf[5] = (short)f32_to_bf16(a1.y);
        xf[6] = (short)f32_to_bf16(a1.z); xf[7] = (short)f32_to_bf16(a1.w);
#pragma unroll
        for (int nt = 0; nt < 8; ++nt) {
            bf16x8 wf = *(const bf16x8*)&Wb[(size_t)(nt * 16 + m) * HID + k0];
            acc[nt] = __builtin_amdgcn_mfma_f32_16x16x32_bf16(wf, xf, acc[nt], 0, 0, 0);
        }
    }

    const int srow = row0 + m;
    const bool ok = srow < N_ITEMS;
#pragma unroll
    for (int nt = 0; nt < 8; ++nt) {
        const int c0 = nt * 16 + q * 4;               // 4 consecutive out cols
        float4 bv = *(const float4*)&bias[c0];
        ushort_t h0 = f32_to_bf16(acc[nt][0] + bv.x);
        ushort_t h1 = f32_to_bf16(acc[nt][1] + bv.y);
        ushort_t h2 = f32_to_bf16(acc[nt][2] + bv.z);
        ushort_t h3 = f32_to_bf16(acc[nt][3] + bv.w);
        uint2 pk;
        pk.x = (uint_t)h0 | ((uint_t)h1 << 16);
        pk.y = (uint_t)h2 | ((uint_t)h3 << 16);
        if (ok) *(uint2*)&S[(size_t)srow * HID + c0] = pk;
    }
}

// === out[row] = sum vals*S[cols] over CSR segment ===
// One wave per row. Lane group g=lane>>4 owns edge slot g; lane l=lane&15 owns
// 8 columns (16B dwordx4). One gather instruction carries FOUR edges (1KB) ->
// 4x data per latency stall, 4x fewer address chains. 16 edges in flight via
// t=0..3 unroll. Tail clamps to the row's last edge (same cache line, v=0).
// Epilogue: shfl_xor(16,32) cross-group reduce, lanes g==0 store 32B.
__global__ __launch_bounds__(256) void spmm_csr(
    const int* __restrict__ cols, const float* __restrict__ vals,
    const int* __restrict__ row_ptr, const ushort_t* __restrict__ S,
    float* __restrict__ out) {
    const int lane = threadIdx.x & 63;
    const int row = blockIdx.x * 4 + ((threadIdx.x >> 6) & 3);
    if (row >= N_ITEMS) return;

    const int g = lane >> 4;        // edge slot within a 4-edge group
    const int l = lane & 15;        // column octet: cols 8*l .. 8*l+7

    const int p0 = row_ptr[row];
    const int p1 = row_ptr[row + 1];

    float acc[8] = {};

    if (p1 > p0) {
        const int last = p1 - 1;
        for (int p = p0; p < p1; p += 16) {
            uint4 u[4]; float v[4];
#pragma unroll
            for (int t = 0; t < 4; ++t) {             // 16 edges in flight
                int idx = p + 4 * t + g;
                bool ok = idx < p1;
                idx = min(idx, last);
                int c = cols[idx];
                v[t] = ok ? vals[idx] : 0.f;
                u[t] = *(const uint4*)&S[(size_t)c * HID + 8 * l];
            }
#pragma unroll
            for (int t = 0; t < 4; ++t) {
                acc[0] = fmaf(v[t], __uint_as_float(u[t].x << 16),          acc[0]);
                acc[1] = fmaf(v[t], __uint_as_float(u[t].x & 0xFFFF0000u),  acc[1]);
                acc[2] = fmaf(v[t], __uint_as_float(u[t].y << 16),          acc[2]);
                acc[3] = fmaf(v[t], __uint_as_float(u[t].y & 0xFFFF0000u),  acc[3]);
                acc[4] = fmaf(v[t], __uint_as_float(u[t].z << 16),          acc[4]);
                acc[5] = fmaf(v[t], __uint_as_float(u[t].z & 0xFFFF0000u),  acc[5]);
                acc[6] = fmaf(v[t], __uint_as_float(u[t].w << 16),          acc[6]);
                acc[7] = fmaf(v[t], __uint_as_float(u[t].w & 0xFFFF0000u),  acc[7]);
            }
        }
    }

    // reduce the 4 edge-groups: lanes l, l+16, l+32, l+48 hold partials
#pragma unroll
    for (int e = 0; e < 8; ++e) {
        acc[e] += __shfl_xor(acc[e], 16, 64);
        acc[e] += __shfl_xor(acc[e], 32, 64);
    }
    if (g == 0) {
        float4 o0 = make_float4(acc[0], acc[1], acc[2], acc[3]);
        float4 o1 = make_float4(acc[4], acc[5], acc[6], acc[7]);
        float* p = &out[(size_t)row * HID + 8 * l];
        *(float4*)p = o0;
        *(float4*)(p + 4) = o1;
    }
}

extern "C" void kernel_launch(void* const* d_in, const int* in_sizes, int n_in,
                              void* d_out, int out_size, void* d_ws, size_t ws_size,
                              hipStream_t stream) {
    const float* X    = (const float*)d_in[0];
    const int*   rows = (const int*)  d_in[1];
    const int*   cols = (const int*)  d_in[2];
    const float* vals = (const float*)d_in[3];
    const float* W    = (const float*)d_in[4];
    const float* bias = (const float*)d_in[5];
    float* out = (float*)d_out;

    ushort_t* Wb      = (ushort_t*)d_ws;                    // 32 KB
    ushort_t* S       = Wb + HID * HID;                     // 25.6 MB bf16
    int*      row_ptr = (int*)(S + (size_t)N_ITEMS * HID);  // 400 KB

    prep<<<PREPW_BLOCKS + RP_BLOCKS, 256, 0, stream>>>(W, rows, Wb, row_ptr);
    gemm_mfma<<<(N_ITEMS + 63) / 64, 256, 0, stream>>>(X, Wb, bias, S);
    spmm_csr<<<(N_ITEMS + 3) / 4, 256, 0, stream>>>(cols, vals, row_ptr, S, out);
}

// Round 8
// 204.714 us; speedup vs baseline: 1.2668x; 1.0533x over previous
//
#include <hip/hip_runtime.h>
#include <hip/hip_fp16.h>

#define N_ITEMS 100000
#define HID 128
#define NNZ_T 1600000
#define PREPW_BLOCKS 64            // 16384 / 256
#define RP_BLOCKS 391              // ceil(100001/256)

typedef unsigned short ushort_t;
typedef unsigned int uint_t;
typedef short bf16x8 __attribute__((ext_vector_type(8)));
typedef float f32x4 __attribute__((ext_vector_type(4)));

static __device__ __forceinline__ ushort_t f32_to_bf16(float f) {
    uint_t u = __float_as_uint(f);
    uint_t r = (u + 0x7FFFu + ((u >> 16) & 1u)) >> 16;   // RNE
    return (ushort_t)r;
}

// === prep: [0..PREPW_BLOCKS) W fp32->bf16 | [PREPW_BLOCKS..) row_ptr ===
__global__ void prep(const float* __restrict__ W, const int* __restrict__ rows,
                     ushort_t* __restrict__ Wb, int* __restrict__ row_ptr) {
    if (blockIdx.x < PREPW_BLOCKS) {
        int i = blockIdx.x * 256 + threadIdx.x;
        Wb[i] = f32_to_bf16(W[i]);
        return;
    }
    int r = (blockIdx.x - PREPW_BLOCKS) * 256 + threadIdx.x;
    if (r > N_ITEMS) return;
    int lo = 0, hi = NNZ_T;
    while (lo < hi) {                       // lower_bound(rows, r), rows sorted
        int mid = (lo + hi) >> 1;
        if (rows[mid] < r) lo = mid + 1; else hi = mid;
    }
    row_ptr[r] = lo;
}

// === S = X @ W^T + b via bf16 MFMA (swapped operands), stored as FP16 ===
// lane(q=lane>>4,m=lane&15) -> item row0+m, out-cols nt*16+q*4..+3
// epilogue: 8 packed 8B fp16 stores per lane.
__global__ __launch_bounds__(256) void gemm_mfma(
    const float* __restrict__ X, const ushort_t* __restrict__ Wb,
    const float* __restrict__ bias, ushort_t* __restrict__ S) {
    const int lane = threadIdx.x & 63;
    const int wave = threadIdx.x >> 6;
    const int m = lane & 15;
    const int q = lane >> 4;
    const int row0 = blockIdx.x * 64 + wave * 16;

    int arow = row0 + m;
    if (arow >= N_ITEMS) arow = N_ITEMS - 1;          // clamp (stores guarded)

    f32x4 acc[8] = {};

#pragma unroll
    for (int kb = 0; kb < 4; ++kb) {
        const int k0 = kb * 32 + q * 8;
        float4 a0 = *(const float4*)&X[(size_t)arow * HID + k0];
        float4 a1 = *(const float4*)&X[(size_t)arow * HID + k0 + 4];
        bf16x8 xf;
        xf[0] = (short)f32_to_bf16(a0.x); xf[1] = (short)f32_to_bf16(a0.y);
        xf[2] = (short)f32_to_bf16(a0.z); xf[3] = (short)f32_to_bf16(a0.w);
        xf[4] = (short)f32_to_bf16(a1.x); xf[5] = (short)f32_to_bf16(a1.y);
        xf[6] = (short)f32_to_bf16(a1.z); xf[7] = (short)f32_to_bf16(a1.w);
#pragma unroll
        for (int nt = 0; nt < 8; ++nt) {
            bf16x8 wf = *(const bf16x8*)&Wb[(size_t)(nt * 16 + m) * HID + k0];
            acc[nt] = __builtin_amdgcn_mfma_f32_16x16x32_bf16(wf, xf, acc[nt], 0, 0, 0);
        }
    }

    const int srow = row0 + m;
    const bool ok = srow < N_ITEMS;
#pragma unroll
    for (int nt = 0; nt < 8; ++nt) {
        const int c0 = nt * 16 + q * 4;               // 4 consecutive out cols
        float4 bv = *(const float4*)&bias[c0];
        ushort_t h0 = __half_as_ushort(__float2half(acc[nt][0] + bv.x));
        ushort_t h1 = __half_as_ushort(__float2half(acc[nt][1] + bv.y));
        ushort_t h2 = __half_as_ushort(__float2half(acc[nt][2] + bv.z));
        ushort_t h3 = __half_as_ushort(__float2half(acc[nt][3] + bv.w));
        uint2 pk;
        pk.x = (uint_t)h0 | ((uint_t)h1 << 16);
        pk.y = (uint_t)h2 | ((uint_t)h3 << 16);
        if (ok) *(uint2*)&S[(size_t)srow * HID + c0] = pk;
    }
}

// === out[row] = sum vals*S[cols] over CSR segment (S in fp16) ===
// One wave per row. Edge window (<=64) loaded with 2 coalesced lane-parallel
// loads, then broadcast per slot via shfl -> zero global edge loads in the hot
// loop. Lane group g=lane>>4 takes slot 4t+g; lane l=lane&15 owns 8 cols (16B).
// Consume = 4 x __hfma2 per edge-quad (packed fp16, ~deg/4 adds per group).
// Cross-group combine in f32 via shfl_xor; lanes g==0 store 32B. No atomics.
__global__ __launch_bounds__(256) void spmm_csr(
    const int* __restrict__ cols, const float* __restrict__ vals,
    const int* __restrict__ row_ptr, const ushort_t* __restrict__ S,
    float* __restrict__ out) {
    const int lane = threadIdx.x & 63;
    const int row = blockIdx.x * 4 + ((threadIdx.x >> 6) & 3);
    if (row >= N_ITEMS) return;

    const int g = lane >> 4;        // edge slot within a quad
    const int l = lane & 15;        // column octet: cols 8*l .. 8*l+7

    const int p0 = row_ptr[row];
    const int p1 = row_ptr[row + 1];

    __half2 acch[4];
    acch[0] = __float2half2_rn(0.f); acch[1] = __float2half2_rn(0.f);
    acch[2] = __float2half2_rn(0.f); acch[3] = __float2half2_rn(0.f);

    for (int w0 = p0; w0 < p1; w0 += 64) {
        const int nw = min(64, p1 - w0);
        // whole window's edge data in registers: 2 coalesced loads
        const int idx = w0 + lane;
        const int c_l = cols[min(idx, p1 - 1)];
        const float v_l = (idx < p1) ? vals[idx] : 0.f;

        for (int s0 = 0; s0 < nw; s0 += 16) {
            uint4 u[4]; float v[4];
#pragma unroll
            for (int t = 0; t < 4; ++t) {             // 16 edges in flight
                const int slot = s0 + 4 * t + g;      // may pad past nw: v=0
                const int c = __shfl(c_l, slot, 64);
                v[t] = __shfl(v_l, slot, 64);
                u[t] = *(const uint4*)&S[(size_t)c * HID + 8 * l];
            }
#pragma unroll
            for (int t = 0; t < 4; ++t) {
                const __half2 vv = __float2half2_rn(v[t]);
                acch[0] = __hfma2(vv, *(const __half2*)&u[t].x, acch[0]);
                acch[1] = __hfma2(vv, *(const __half2*)&u[t].y, acch[1]);
                acch[2] = __hfma2(vv, *(const __half2*)&u[t].z, acch[2]);
                acch[3] = __hfma2(vv, *(const __half2*)&u[t].w, acch[3]);
            }
        }
    }

    // unpack to f32, reduce the 4 edge-groups (lanes l, l+16, l+32, l+48)
    float acc[8];
#pragma unroll
    for (int j = 0; j < 4; ++j) {
        acc[2 * j]     = __low2float(acch[j]);
        acc[2 * j + 1] = __high2float(acch[j]);
    }
#pragma unroll
    for (int e = 0; e < 8; ++e) {
        acc[e] += __shfl_xor(acc[e], 16, 64);
        acc[e] += __shfl_xor(acc[e], 32, 64);
    }
    if (g == 0) {
        float* p = &out[(size_t)row * HID + 8 * l];
        *(float4*)p       = make_float4(acc[0], acc[1], acc[2], acc[3]);
        *(float4*)(p + 4) = make_float4(acc[4], acc[5], acc[6], acc[7]);
    }
}

extern "C" void kernel_launch(void* const* d_in, const int* in_sizes, int n_in,
                              void* d_out, int out_size, void* d_ws, size_t ws_size,
                              hipStream_t stream) {
    const float* X    = (const float*)d_in[0];
    const int*   rows = (const int*)  d_in[1];
    const int*   cols = (const int*)  d_in[2];
    const float* vals = (const float*)d_in[3];
    const float* W    = (const float*)d_in[4];
    const float* bias = (const float*)d_in[5];
    float* out = (float*)d_out;

    ushort_t* Wb      = (ushort_t*)d_ws;                    // 32 KB (bf16)
    ushort_t* S       = Wb + HID * HID;                     // 25.6 MB (fp16)
    int*      row_ptr = (int*)(S + (size_t)N_ITEMS * HID);  // 400 KB

    prep<<<PREPW_BLOCKS + RP_BLOCKS, 256, 0, stream>>>(W, rows, Wb, row_ptr);
    gemm_mfma<<<(N_ITEMS + 63) / 64, 256, 0, stream>>>(X, Wb, bias, S);
    spmm_csr<<<(N_ITEMS + 3) / 4, 256, 0, stream>>>(cols, vals, row_ptr, S, out);
}

// Round 9
// 203.134 us; speedup vs baseline: 1.2767x; 1.0078x over previous
//
#include <hip/hip_runtime.h>
#include <hip/hip_fp16.h>

#define N_ITEMS 100000
#define HID 128
#define NNZ_T 1600000
#define PREPW_BLOCKS 64            // 16384 / 256
#define RP_BLOCKS 391              // ceil(100001/256)

typedef unsigned short ushort_t;
typedef unsigned int uint_t;
typedef short bf16x8 __attribute__((ext_vector_type(8)));
typedef float f32x4 __attribute__((ext_vector_type(4)));

static __device__ __forceinline__ ushort_t f32_to_bf16(float f) {
    uint_t u = __float_as_uint(f);
    uint_t r = (u + 0x7FFFu + ((u >> 16) & 1u)) >> 16;   // RNE
    return (ushort_t)r;
}

// === prep: [0..PREPW_BLOCKS) W fp32->bf16 | [PREPW_BLOCKS..) row_ptr ===
__global__ void prep(const float* __restrict__ W, const int* __restrict__ rows,
                     ushort_t* __restrict__ Wb, int* __restrict__ row_ptr) {
    if (blockIdx.x < PREPW_BLOCKS) {
        int i = blockIdx.x * 256 + threadIdx.x;
        Wb[i] = f32_to_bf16(W[i]);
        return;
    }
    int r = (blockIdx.x - PREPW_BLOCKS) * 256 + threadIdx.x;
    if (r > N_ITEMS) return;
    int lo = 0, hi = NNZ_T;
    while (lo < hi) {                       // lower_bound(rows, r), rows sorted
        int mid = (lo + hi) >> 1;
        if (rows[mid] < r) lo = mid + 1; else hi = mid;
    }
    row_ptr[r] = lo;
}

// === S = X @ W^T + b via bf16 MFMA (swapped operands), stored as FP16 ===
// lane(q=lane>>4,m=lane&15) -> item row0+m, out-cols nt*16+q*4..+3
// epilogue: 8 packed 8B fp16 stores per lane.  (unchanged from round 8)
__global__ __launch_bounds__(256) void gemm_mfma(
    const float* __restrict__ X, const ushort_t* __restrict__ Wb,
    const float* __restrict__ bias, ushort_t* __restrict__ S) {
    const int lane = threadIdx.x & 63;
    const int wave = threadIdx.x >> 6;
    const int m = lane & 15;
    const int q = lane >> 4;
    const int row0 = blockIdx.x * 64 + wave * 16;

    int arow = row0 + m;
    if (arow >= N_ITEMS) arow = N_ITEMS - 1;          // clamp (stores guarded)

    f32x4 acc[8] = {};

#pragma unroll
    for (int kb = 0; kb < 4; ++kb) {
        const int k0 = kb * 32 + q * 8;
        float4 a0 = *(const float4*)&X[(size_t)arow * HID + k0];
        float4 a1 = *(const float4*)&X[(size_t)arow * HID + k0 + 4];
        bf16x8 xf;
        xf[0] = (short)f32_to_bf16(a0.x); xf[1] = (short)f32_to_bf16(a0.y);
        xf[2] = (short)f32_to_bf16(a0.z); xf[3] = (short)f32_to_bf16(a0.w);
        xf[4] = (short)f32_to_bf16(a1.x); xf[5] = (short)f32_to_bf16(a1.y);
        xf[6] = (short)f32_to_bf16(a1.z); xf[7] = (short)f32_to_bf16(a1.w);
#pragma unroll
        for (int nt = 0; nt < 8; ++nt) {
            bf16x8 wf = *(const bf16x8*)&Wb[(size_t)(nt * 16 + m) * HID + k0];
            acc[nt] = __builtin_amdgcn_mfma_f32_16x16x32_bf16(wf, xf, acc[nt], 0, 0, 0);
        }
    }

    const int srow = row0 + m;
    const bool ok = srow < N_ITEMS;
#pragma unroll
    for (int nt = 0; nt < 8; ++nt) {
        const int c0 = nt * 16 + q * 4;               // 4 consecutive out cols
        float4 bv = *(const float4*)&bias[c0];
        ushort_t h0 = __half_as_ushort(__float2half(acc[nt][0] + bv.x));
        ushort_t h1 = __half_as_ushort(__float2half(acc[nt][1] + bv.y));
        ushort_t h2 = __half_as_ushort(__float2half(acc[nt][2] + bv.z));
        ushort_t h3 = __half_as_ushort(__float2half(acc[nt][3] + bv.w));
        uint2 pk;
        pk.x = (uint_t)h0 | ((uint_t)h1 << 16);
        pk.y = (uint_t)h2 | ((uint_t)h3 << 16);
        if (ok) *(uint2*)&S[(size_t)srow * HID + c0] = pk;
    }
}

// === out[row] = sum vals*S[cols] over CSR segment (S in fp16) ===
// TWO rows per wave, interleaved: one coalesced (cols,vals) load fills BOTH
// rows' 16-slot windows (lanes 0-31 dup row A slots 0-15, lanes 32-63 row B);
// shfl broadcasts per slot. Lane: g=lane>>4 edge-slot-in-quad, l=lane&15 owns
// 8 cols (16B). Per window: 8 independent quad-gathers in flight (4 per row).
// Padded slots clamp to a valid edge (same line -> L1 hit) with v=0.
// fp16 packed accumulate; f32 cross-group reduce; no atomics; empty rows -> 0.
__global__ __launch_bounds__(256) void spmm_csr(
    const int* __restrict__ cols, const float* __restrict__ vals,
    const int* __restrict__ row_ptr, const ushort_t* __restrict__ S,
    float* __restrict__ out) {
    const int lane = threadIdx.x & 63;
    const int wid = blockIdx.x * 4 + ((threadIdx.x >> 6) & 3);
    const int r0 = wid * 2;                 // rows r0, r0+1
    if (r0 >= N_ITEMS) return;

    const int g = lane >> 4;                // edge slot within a quad (0..3)
    const int l = lane & 15;                // column octet: cols 8*l .. 8*l+7
    const int sel = lane >> 5;              // 0: window A, 1: window B

    const int2 p01 = *(const int2*)&row_ptr[r0];      // r0 even -> 8B aligned
    const int pEb = row_ptr[r0 + 2];                  // r0+2 <= N_ITEMS: valid
    int pa = p01.x; const int pEa = p01.y;
    int pb = p01.y;

    __half2 accA[4], accB[4];
#pragma unroll
    for (int j = 0; j < 4; ++j) { accA[j] = __float2half2_rn(0.f); accB[j] = __float2half2_rn(0.f); }

    while (pa < pEa || pb < pEb) {
        // one coalesced load pair fills both rows' windows
        const int base = sel ? pb : pa;
        const int end  = sel ? pEb : pEa;
        const int idx  = base + (lane & 15);
        const int cidx = max(min(idx, end - 1), 0);   // clamp (empty-row safe)
        const int c_l  = cols[cidx];
        const float v_l = (idx < end) ? vals[cidx] : 0.f;

        uint4 uA[4], uB[4];
        float vA[4], vB[4];
#pragma unroll
        for (int t = 0; t < 4; ++t) {                 // 8 quad-gathers in flight
            const int sa = 4 * t + g;                 // slot in window A (lane 0-15)
            const int ca = __shfl(c_l, sa, 64);
            vA[t] = __shfl(v_l, sa, 64);
            uA[t] = *(const uint4*)&S[(size_t)ca * HID + 8 * l];
            const int cb = __shfl(c_l, 32 + sa, 64);  // window B (lane 32-47)
            vB[t] = __shfl(v_l, 32 + sa, 64);
            uB[t] = *(const uint4*)&S[(size_t)cb * HID + 8 * l];
        }
#pragma unroll
        for (int t = 0; t < 4; ++t) {
            const __half2 wa = __float2half2_rn(vA[t]);
            accA[0] = __hfma2(wa, *(const __half2*)&uA[t].x, accA[0]);
            accA[1] = __hfma2(wa, *(const __half2*)&uA[t].y, accA[1]);
            accA[2] = __hfma2(wa, *(const __half2*)&uA[t].z, accA[2]);
            accA[3] = __hfma2(wa, *(const __half2*)&uA[t].w, accA[3]);
            const __half2 wb = __float2half2_rn(vB[t]);
            accB[0] = __hfma2(wb, *(const __half2*)&uB[t].x, accB[0]);
            accB[1] = __hfma2(wb, *(const __half2*)&uB[t].y, accB[1]);
            accB[2] = __hfma2(wb, *(const __half2*)&uB[t].z, accB[2]);
            accB[3] = __hfma2(wb, *(const __half2*)&uB[t].w, accB[3]);
        }
        pa = min(pa + 16, pEa);
        pb = min(pb + 16, pEb);
    }

    // unpack to f32; xor-reduce over the 4 edge-groups (lanes l,l+16,l+32,l+48)
    float fA[8], fB[8];
#pragma unroll
    for (int j = 0; j < 4; ++j) {
        fA[2 * j] = __low2float(accA[j]);  fA[2 * j + 1] = __high2float(accA[j]);
        fB[2 * j] = __low2float(accB[j]);  fB[2 * j + 1] = __high2float(accB[j]);
    }
#pragma unroll
    for (int e = 0; e < 8; ++e) {
        fA[e] += __shfl_xor(fA[e], 16, 64);
        fA[e] += __shfl_xor(fA[e], 32, 64);
        fB[e] += __shfl_xor(fB[e], 16, 64);
        fB[e] += __shfl_xor(fB[e], 32, 64);
    }
    if (g == 0) {                                     // lanes 0-15: row A
        float* p = &out[(size_t)r0 * HID + 8 * l];
        *(float4*)p       = make_float4(fA[0], fA[1], fA[2], fA[3]);
        *(float4*)(p + 4) = make_float4(fA[4], fA[5], fA[6], fA[7]);
    } else if (g == 1 && r0 + 1 < N_ITEMS) {          // lanes 16-31: row B
        float* p = &out[(size_t)(r0 + 1) * HID + 8 * l];
        *(float4*)p       = make_float4(fB[0], fB[1], fB[2], fB[3]);
        *(float4*)(p + 4) = make_float4(fB[4], fB[5], fB[6], fB[7]);
    }
}

extern "C" void kernel_launch(void* const* d_in, const int* in_sizes, int n_in,
                              void* d_out, int out_size, void* d_ws, size_t ws_size,
                              hipStream_t stream) {
    const float* X    = (const float*)d_in[0];
    const int*   rows = (const int*)  d_in[1];
    const int*   cols = (const int*)  d_in[2];
    const float* vals = (const float*)d_in[3];
    const float* W    = (const float*)d_in[4];
    const float* bias = (const float*)d_in[5];
    float* out = (float*)d_out;

    ushort_t* Wb      = (ushort_t*)d_ws;                    // 32 KB (bf16)
    ushort_t* S       = Wb + HID * HID;                     // 25.6 MB (fp16)
    int*      row_ptr = (int*)(S + (size_t)N_ITEMS * HID);  // 400 KB

    prep<<<PREPW_BLOCKS + RP_BLOCKS, 256, 0, stream>>>(W, rows, Wb, row_ptr);
    gemm_mfma<<<(N_ITEMS + 63) / 64, 256, 0, stream>>>(X, Wb, bias, S);
    spmm_csr<<<(N_ITEMS / 2 + 3) / 4, 256, 0, stream>>>(cols, vals, row_ptr, S, out);
}